// Round 6
// baseline (159.729 us; speedup 1.0000x reference)
//
#include <hip/hip_runtime.h>

// AnnularDilatedKNN: B=4, N=4096, C=64, SAMPLE=16, DILATED_RATE=2, r^2=256.
// Round 6: point-per-lane bitmask query (no ballots/branches in hot loop),
// wave-uniform scalar candidate loads, LDS bitmask, serial rank extraction,
// fused gather. Numerics bit-match numpy: contract off, sq=(x*x+y*y)+z*z,
// dot=(xi*xj+yi*yj)+zi*zj, d2=(sqi+sqj)-2*dot.

#define BB 4
#define NN 4096
#define KK 16
#define PPB 64                  // points per block
#define THREADS 512             // 8 waves; wave w scans slice w
#define SLICE 512               // candidates per wave
#define NWORD 128               // 4096 bits per point
#define WPP 129                 // padded words/point (bank-conflict-free)
#define SROW 17                 // padded sids row stride
#define PLANE (NN * KK)         // 65536

// ---------- K1: P[b*N+j] = (x, y, z, sq) ----------
__global__ __launch_bounds__(256)
void build_soa(const float* __restrict__ xyz, float4* __restrict__ P)
{
#pragma clang fp contract(off)
    const int g = blockIdx.x * 256 + threadIdx.x;      // 0..16383
    const float x = xyz[3 * g], y = xyz[3 * g + 1], z = xyz[3 * g + 2];
    const float sq = (x * x + y * y) + z * z;
    P[g] = make_float4(x, y, z, sq);
}

// ---------- K2: fused bitmask query + rank extraction + gather ----------
__global__ __launch_bounds__(THREADS)
void query_gather(const float4* __restrict__ P, const float* __restrict__ feat,
                  float* __restrict__ out)
{
#pragma clang fp contract(off)
    __shared__ unsigned smask[PPB * WPP];   // 33 KB hit bitmasks
    __shared__ int      sids[PPB * SROW];   // padded ids rows

    const int blk  = blockIdx.x;            // 0..255
    const int b    = blk >> 6;              // 64 blocks per batch
    const int i0   = (blk & 63) * PPB;      // first point (in batch)
    const int t    = threadIdx.x;
    const int lane = t & 63;
    const int wave = t >> 6;                // slice id 0..7

    const float4* Pb = P + (b << 12);

    // ---- phase 1: lane owns point i0+lane; wave scans its candidate slice ----
    {
        const float4 pi = Pb[i0 + lane];
        const int jbase = wave * SLICE;
        const int wbase = jbase >> 5;        // first word of this slice

        for (int w = 0; w < SLICE / 32; ++w) {
            const int j0 = jbase + (w << 5);
            unsigned mw = 0;
#pragma unroll
            for (int q = 0; q < 32; ++q) {
                const float4 pj = Pb[j0 + q];          // wave-uniform -> scalar load
                const float dot = (pi.x * pj.x + pi.y * pj.y) + pi.z * pj.z;
                const float d2  = (pi.w + pj.w) - 2.0f * dot;
                if (d2 < 256.0f) mw |= (1u << q);
            }
            smask[lane * WPP + wbase + w] = mw;
        }
    }
    __syncthreads();

    // ---- phase 2: wave 0, lane = point; extract rank 0 and ranks 16..30 ----
    if (wave == 0) {
        const unsigned* mrow = &smask[lane * WPP];
        int* row = sids + lane * SROW;
        int h0 = -1;
        int r  = 0;                          // hits consumed so far
        for (int w = 0; w < NWORD; ++w) {
            unsigned word = mrow[w];
            if (!word) continue;
            if (h0 < 0) h0 = (w << 5) + __builtin_ctz(word);
            const int c = __builtin_popcount(word);
            if (r + c <= 16) { r += c; continue; }   // whole word below rank 16
            while (word) {
                const int bit = __builtin_ctz(word);
                word &= word - 1;
                if (r >= 16) row[r - 15] = (w << 5) + bit;
                if (++r > 30) break;
            }
            if (r > 30) break;
        }
        row[0] = h0;                          // center slot (first hit, always exists)
        const int hi = (r < 31 ? r : 31) - 16; // last filled slot
        for (int s = (hi < 0 ? 1 : hi + 1); s <= 15; ++s) row[s] = h0;
    }
    __syncthreads();

    // ---- gather phase: 1024 output rows; thread handles rows t and t+512 ----
#pragma unroll
    for (int rr = 0; rr < 2; ++rr) {
        const int rowi = t + rr * THREADS;            // pt*16 + k
        const int id   = sids[(rowi >> 4) * SROW + (rowi & 15)];
        const int ob   = i0 * KK + rowi;              // offset in each [N*K] plane

        const float4 p = Pb[id];
        float* o0 = out + (size_t)b * 3 * PLANE + ob;
        o0[0]         = p.x;
        o0[PLANE]     = p.y;
        o0[2 * PLANE] = p.z;

        const float4* frow = reinterpret_cast<const float4*>(feat + ((size_t)(b << 12) + id) * 64);
        float* o1 = out + (size_t)BB * 3 * PLANE + (size_t)b * 64 * PLANE + ob;
#pragma unroll
        for (int q = 0; q < 16; ++q) {
            const float4 v = frow[q];
            float* oc = o1 + (size_t)(4 * q) * PLANE;
            oc[0]         = v.x;
            oc[PLANE]     = v.y;
            oc[2 * PLANE] = v.z;
            oc[3 * PLANE] = v.w;
        }
    }
}

extern "C" void kernel_launch(void* const* d_in, const int* in_sizes, int n_in,
                              void* d_out, int out_size, void* d_ws, size_t ws_size,
                              hipStream_t stream) {
    const float* xyz  = (const float*)d_in[0];
    const float* feat = (const float*)d_in[1];
    float* out = (float*)d_out;

    float4* P = (float4*)d_ws;                       // 256 KB

    build_soa   <<<BB * NN / 256, 256, 0, stream>>>(xyz, P);
    query_gather<<<BB * NN / PPB, THREADS, 0, stream>>>(P, feat, out);  // 256 blocks
}

// Round 7
// 121.666 us; speedup vs baseline: 1.3128x; 1.3128x over previous
//
#include <hip/hip_runtime.h>

// AnnularDilatedKNN: B=4, N=4096, C=64, SAMPLE=16, DILATED_RATE=2, r^2=256.
// Round 7: branch-free ballot-recording query.
//  - block = 256 thr = 4 waves = 8 points; wave pair covers a 4-point group,
//    each wave scans HALF the candidate range (32 chunks) -> 8192 waves (8/SIMD)
//    with 4x load amortization (268 MB total).
//  - hot loop records raw 64-bit ballots into LDS (stride-65 padded); no cnt,
//    no branches, no early exit -> fully pipelineable.
//  - rank extraction (R6 phase-2 logic, bit-exact) on 8 thr/block, then the
//    proven coalesced gather.
// Numerics bit-match numpy: contract off, sq=(x*x+y*y)+z*z,
// dot=(xi*xj+yi*yj)+zi*zj, d2=(sqi+sqj)-2*dot.

#define BB 4
#define NN 4096
#define KK 16
#define PPB 8                   // points per block
#define NWORD 64                // 64-bit words per point (4096 bits)
#define MSTR 65                 // padded lmask row stride
#define PLANE (NN * KK)         // 65536

// ---------- K1: P[b*N+j] = (x, y, z, sq) ----------
__global__ __launch_bounds__(256)
void build_soa(const float* __restrict__ xyz, float4* __restrict__ P)
{
#pragma clang fp contract(off)
    const int g = blockIdx.x * 256 + threadIdx.x;      // 0..16383
    const float x = xyz[3 * g], y = xyz[3 * g + 1], z = xyz[3 * g + 2];
    const float sq = (x * x + y * y) + z * z;
    P[g] = make_float4(x, y, z, sq);
}

// ---------- K2: fused ballot query + extraction + gather ----------
__global__ __launch_bounds__(256)
void query_gather(const float4* __restrict__ P, const float* __restrict__ feat,
                  float* __restrict__ out)
{
#pragma clang fp contract(off)
    __shared__ unsigned long long lmask[PPB * MSTR];   // 4.2 KB raw hit masks
    __shared__ int sids[PPB * KK];

    const int blk  = blockIdx.x;            // 0..2047
    const int b    = blk >> 9;              // 512 blocks per batch
    const int i0   = (blk & 511) * PPB;     // first point (in batch)
    const int t    = threadIdx.x;
    const int lane = t & 63;
    const int wave = t >> 6;
    const int grp  = wave >> 1;             // 4-point group 0/1
    const int half = wave & 1;              // candidate half 0/1

    const float4* Pb = P + (b << 12);

    // ---- phase 1: record raw ballots, branch-free fixed loop ----
    {
        const int pb = i0 + grp * 4;
        const float4 pi0 = Pb[pb + 0];
        const float4 pi1 = Pb[pb + 1];
        const float4 pi2 = Pb[pb + 2];
        const float4 pi3 = Pb[pb + 3];
        const int jc0 = half * 32;          // first chunk of this wave's range

        float4 cur = Pb[(jc0 << 6) + lane];
        unsigned long long* lm = &lmask[(grp * 4) * MSTR + jc0];

        for (int c = 0; c < 32; ++c) {
            const float4 a = cur;
            cur = Pb[((jc0 + ((c + 1) & 31)) << 6) + lane];   // wrap prefetch

            const float dot0 = (pi0.x * a.x + pi0.y * a.y) + pi0.z * a.z;
            const float d20  = (pi0.w + a.w) - 2.0f * dot0;
            const float dot1 = (pi1.x * a.x + pi1.y * a.y) + pi1.z * a.z;
            const float d21  = (pi1.w + a.w) - 2.0f * dot1;
            const float dot2 = (pi2.x * a.x + pi2.y * a.y) + pi2.z * a.z;
            const float d22  = (pi2.w + a.w) - 2.0f * dot2;
            const float dot3 = (pi3.x * a.x + pi3.y * a.y) + pi3.z * a.z;
            const float d23  = (pi3.w + a.w) - 2.0f * dot3;

            const unsigned long long m0 = __ballot(d20 < 256.0f);
            const unsigned long long m1 = __ballot(d21 < 256.0f);
            const unsigned long long m2 = __ballot(d22 < 256.0f);
            const unsigned long long m3 = __ballot(d23 < 256.0f);

            if (lane == 0) {                // uniform values, single-lane store
                lm[c]            = m0;
                lm[c + MSTR]     = m1;
                lm[c + 2 * MSTR] = m2;
                lm[c + 3 * MSTR] = m3;
            }
        }
    }
    __syncthreads();

    // ---- phase 2: threads 0..7 extract rank 0 and ranks 16..30 for point t ----
    if (t < PPB) {
        const unsigned long long* mrow = &lmask[t * MSTR];
        int* row = sids + t * KK;
        int h0 = -1;
        int r  = 0;                          // hits consumed so far
        for (int w = 0; w < NWORD; ++w) {
            unsigned long long word = mrow[w];
            if (!word) continue;
            if (h0 < 0) h0 = (w << 6) + (int)__builtin_ctzll(word);
            const int c = __builtin_popcountll(word);
            if (r + c <= 16) { r += c; continue; }    // whole word below rank 16
            while (word) {
                const int bit = __builtin_ctzll(word);
                word &= word - 1;
                if (r >= 16) row[r - 15] = (w << 6) + bit;
                if (++r > 30) break;
            }
            if (r > 30) break;
        }
        row[0] = h0;                          // center slot (self-hit guarantees h0>=0)
        const int hi = (r < 31 ? r : 31) - 16;
        for (int s = (hi < 0 ? 1 : hi + 1); s <= 15; ++s) row[s] = h0;
    }
    __syncthreads();

    // ---- phase 3: gather; 128 rows, 2 channel-halves ----
    const int rowi = t & 127;               // pt*16 + k
    const int part = t >> 7;                // 0/1 -> channels [32*part, 32*part+32)
    const int id   = sids[rowi];            // sids is exactly 8*16 = 128 ints
    const int ob   = i0 * KK + rowi;        // offset inside each [N*K] plane

    if (part == 0) {                        // dilated_xyz [B,3,N,K]
        const float4 p = Pb[id];
        float* o0 = out + (size_t)b * 3 * PLANE + ob;
        o0[0]         = p.x;
        o0[PLANE]     = p.y;
        o0[2 * PLANE] = p.z;
    }

    const float4* frow = reinterpret_cast<const float4*>(feat + ((size_t)(b << 12) + id) * 64) + part * 8;
    float* o1 = out + (size_t)BB * 3 * PLANE + (size_t)b * 64 * PLANE
                    + (size_t)(part * 32) * PLANE + ob;
#pragma unroll
    for (int q = 0; q < 8; ++q) {
        const float4 v = frow[q];
        float* oc = o1 + (size_t)(4 * q) * PLANE;
        oc[0]         = v.x;
        oc[PLANE]     = v.y;
        oc[2 * PLANE] = v.z;
        oc[3 * PLANE] = v.w;
    }
}

extern "C" void kernel_launch(void* const* d_in, const int* in_sizes, int n_in,
                              void* d_out, int out_size, void* d_ws, size_t ws_size,
                              hipStream_t stream) {
    const float* xyz  = (const float*)d_in[0];
    const float* feat = (const float*)d_in[1];
    float* out = (float*)d_out;

    float4* P = (float4*)d_ws;                       // 256 KB

    build_soa   <<<BB * NN / 256, 256, 0, stream>>>(xyz, P);
    query_gather<<<BB * NN / PPB, 256, 0, stream>>>(P, feat, out);   // 2048 blocks
}